// Round 4
// baseline (1091.544 us; speedup 1.0000x reference)
//
#include <hip/hip_runtime.h>
#include <hip/hip_bf16.h>

typedef unsigned short u16;
typedef __bf16 bf16_t;
typedef _Float16 half_t;
typedef __bf16 v8bf __attribute__((ext_vector_type(8)));
typedef _Float16 v8h __attribute__((ext_vector_type(8)));
typedef float v4fl __attribute__((ext_vector_type(4)));
typedef float v4f __attribute__((ext_vector_type(4)));

#define BM 128
#define BN 128
#define BK 32

__device__ __forceinline__ float ternq(float w, float s) {
    float q = rintf(w / s);                 // true division: match jnp boundary
    return fminf(1.f, fmaxf(-1.f, q));
}

// ---------------- stage 1: per-block partial sum of |w| (deterministic) ----------
__global__ void abssum_partial(const float* __restrict__ w, long n,
                               float* __restrict__ partial) {
    long i0 = ((long)blockIdx.x * 256 + threadIdx.x) * 8;
    long stride = (long)gridDim.x * 256 * 8;
    float s = 0.f;
    for (long i = i0; i < n; i += stride) {
        v4fl a = *(const v4fl*)(w + i);
        v4fl b = *(const v4fl*)(w + i + 4);
#pragma unroll
        for (int j = 0; j < 4; ++j) s += fabsf(a[j]) + fabsf(b[j]);
    }
#pragma unroll
    for (int off = 32; off > 0; off >>= 1) s += __shfl_down(s, off, 64);
    __shared__ __align__(16) float red[4];
    if ((threadIdx.x & 63) == 0) red[threadIdx.x >> 6] = s;
    __syncthreads();
    if (threadIdx.x == 0)
        partial[blockIdx.x] = (red[0] + red[1]) + (red[2] + red[3]);
}

// ---------------- stage 2: combine 256 partials per matrix, fixed order -----------
// wave 0 -> scales[0] (w_up), wave 1 -> scales[1] (w_dn). Writes pre-clipped s.
__global__ void abssum_final(const float* __restrict__ part_up,
                             const float* __restrict__ part_dn,
                             float* __restrict__ scales, float inv) {
    const int wv = threadIdx.x >> 6;
    const int l = threadIdx.x & 63;
    const float* part = wv ? part_dn : part_up;
    float s = ((part[l] + part[l + 64]) + (part[l + 128] + part[l + 192]));
#pragma unroll
    for (int off = 32; off > 0; off >>= 1) s += __shfl_down(s, off, 64);
    if (l == 0) scales[wv] = fmaxf(s * inv, 1e-5f);
}

// ---------------- ternary weight quant fp32 -> bf16 {-1,0,1} ----------------
__global__ void wquant_kernel(const float* __restrict__ w, u16* __restrict__ wq,
                              const float* __restrict__ scale) {
    float s = scale[0];
    long i = ((long)blockIdx.x * 256 + threadIdx.x) * 8;
    v4fl a = *(const v4fl*)(w + i);
    v4fl b = *(const v4fl*)(w + i + 4);
    v8bf o;
#pragma unroll
    for (int j = 0; j < 4; ++j) {
        o[j]     = (bf16_t)ternq(a[j], s);
        o[j + 4] = (bf16_t)ternq(b[j], s);
    }
    *(v8bf*)(wq + i) = o;
}

// ---------------- per-token act quant fp32 -> bf16 ints, width 2048 ----------------
__global__ void aquant_kernel(const float* __restrict__ src, u16* __restrict__ dst,
                              float* __restrict__ scale_out) {
    const int row = blockIdx.x;
    const int tid = threadIdx.x;
    const float* p = src + (size_t)row * 2048;
    float v[8];
    {
        v4fl a = *(const v4fl*)(p + tid * 8);
        v4fl b = *(const v4fl*)(p + tid * 8 + 4);
#pragma unroll
        for (int j = 0; j < 4; ++j) { v[j] = a[j]; v[j + 4] = b[j]; }
    }
    float amax = 0.f;
#pragma unroll
    for (int j = 0; j < 8; ++j) amax = fmaxf(amax, fabsf(v[j]));
#pragma unroll
    for (int off = 32; off > 0; off >>= 1) amax = fmaxf(amax, __shfl_xor(amax, off, 64));
    __shared__ __align__(16) float red[4];
    __shared__ float bsc;
    if ((tid & 63) == 0) red[tid >> 6] = amax;
    __syncthreads();
    if (tid == 0) {
        float m = fmaxf(fmaxf(red[0], red[1]), fmaxf(red[2], red[3]));
        m = fmaxf(m, 1e-5f);
        scale_out[row] = m / 127.f;
        bsc = 127.f / m;
    }
    __syncthreads();
    float sc = bsc;
    v8bf o;
#pragma unroll
    for (int j = 0; j < 8; ++j) {
        float t = rintf(v[j] * sc);
        o[j] = (bf16_t)fminf(127.f, fmaxf(-127.f, t));
    }
    *(v8bf*)(dst + (size_t)row * 2048 + tid * 8) = o;
}

// ---------------- per-row amax of h (width = NV*2048), emit scale & recip ---------
template <typename T, int NV>
__global__ void hamax_kernel(const T* __restrict__ h, float* __restrict__ scale_out,
                             float* __restrict__ recip_out) {
    const int row = blockIdx.x;
    const int tid = threadIdx.x;
    const T* p = h + (size_t)row * (NV * 2048);
    float amax = 0.f;
#pragma unroll
    for (int it = 0; it < NV; ++it) {
        const T* s = p + ((size_t)it * 256 + tid) * 8;
#pragma unroll
        for (int j = 0; j < 8; ++j) amax = fmaxf(amax, fabsf((float)s[j]));
    }
#pragma unroll
    for (int off = 32; off > 0; off >>= 1) amax = fmaxf(amax, __shfl_xor(amax, off, 64));
    __shared__ __align__(16) float red[4];
    if ((tid & 63) == 0) red[tid >> 6] = amax;
    __syncthreads();
    if (tid == 0) {
        float m = fmaxf(fmaxf(red[0], red[1]), fmaxf(red[2], red[3]));
        m = fmaxf(m, 1e-5f);
        scale_out[row] = m / 127.f;
        recip_out[row] = 127.f / m;
    }
}

// ---------------- GEMM: C[M,N] = A[M,K] * B[N,K]^T -> MFMA bf16 ----------------
// ASRC: 0 = A bf16 ints; 1 = A fp32 quantize-on-stage; 2 = A fp16 quantize-on-stage.
// EPI:  0 = out fp32 = acc*sw*rowscale; 1 = h fp16 = relu(...)^2; 2 = h fp32 = relu(...)^2.
template <int ASRC, int EPI>
__launch_bounds__(256, 2)
__global__ void gemm_bt(const void* __restrict__ Av, const u16* __restrict__ B,
                        void* __restrict__ Cv,
                        const float* __restrict__ rowscale,
                        const float* __restrict__ arecip,
                        const float* __restrict__ wscale,
                        int M, int N, int K) {
    __shared__ __align__(16) u16 As[BM * BK];   // 8 KB
    __shared__ __align__(16) u16 Bs[BN * BK];   // 8 KB

    const int tid = threadIdx.x;
    const int w = tid >> 6;
    const int l = tid & 63;
    const int m0 = blockIdx.y * BM;
    const int n0 = blockIdx.x * BN;

    // staging: waves 0,1 -> As; waves 2,3 -> Bs. Each lane: 4 chunks of 8 elems.
    const bool isA = (w < 2);
    const int srow = (isA ? w * 64 : (w - 2) * 64) + (l >> 2);
    const int scol = (l & 3) * 8;
    u16* ldst = (isA ? As : Bs) + srow * BK + scol;

    const size_t arowoff = (size_t)(m0 + srow) * K + scol;
    const u16*    gA16 = (const u16*)Av + arowoff;
    const float*  gA32 = (const float*)Av + arowoff;
    const half_t* gAh  = (const half_t*)Av + arowoff;
    const u16*    gB   = B + (size_t)(n0 + srow) * K + scol;

    float scj[4] = {0.f, 0.f, 0.f, 0.f};
    if (ASRC != 0) {
        if (isA) {
#pragma unroll
            for (int j = 0; j < 4; ++j) scj[j] = arecip[m0 + srow + j * 16];
        }
    }

    // compute role: wave (wr,wc) owns 64x64; 4x4 of 16x16x32 tiles
    const int wr = w >> 1, wc = w & 1;
    const int lrow = l & 15, lq = l >> 4;

    v4f acc[4][4];
#pragma unroll
    for (int a = 0; a < 4; ++a)
#pragma unroll
        for (int b = 0; b < 4; ++b) acc[a][b] = (v4f){0.f, 0.f, 0.f, 0.f};

    const int kiters = K / BK;
    for (int kt = 0; kt < kiters; ++kt) {
        v8bf r[4];
        if (isA) {
            if (ASRC == 0) {
#pragma unroll
                for (int j = 0; j < 4; ++j)
                    r[j] = *(const v8bf*)(gA16 + (size_t)j * 16 * K + kt * BK);
            } else if (ASRC == 1) {
#pragma unroll
                for (int j = 0; j < 4; ++j) {
                    const float* s = gA32 + (size_t)j * 16 * K + kt * BK;
                    v4fl f0 = *(const v4fl*)s;
                    v4fl f1 = *(const v4fl*)(s + 4);
#pragma unroll
                    for (int e = 0; e < 4; ++e) {
                        float t0 = rintf(f0[e] * scj[j]);
                        float t1 = rintf(f1[e] * scj[j]);
                        r[j][e]     = (bf16_t)fminf(127.f, fmaxf(-127.f, t0));
                        r[j][e + 4] = (bf16_t)fminf(127.f, fmaxf(-127.f, t1));
                    }
                }
            } else {
#pragma unroll
                for (int j = 0; j < 4; ++j) {
                    v8h hv = *(const v8h*)(gAh + (size_t)j * 16 * K + kt * BK);
#pragma unroll
                    for (int e = 0; e < 8; ++e) {
                        float t = rintf((float)hv[e] * scj[j]);
                        r[j][e] = (bf16_t)fminf(127.f, fmaxf(-127.f, t));
                    }
                }
            }
        } else {
#pragma unroll
            for (int j = 0; j < 4; ++j)
                r[j] = *(const v8bf*)(gB + (size_t)j * 16 * K + kt * BK);
        }
        __syncthreads();   // previous iteration's fragment reads complete
#pragma unroll
        for (int j = 0; j < 4; ++j)
            *(v8bf*)(ldst + j * 16 * BK) = r[j];
        __syncthreads();   // staging visible

        v8bf af[4], bfr[4];
#pragma unroll
        for (int mi = 0; mi < 4; ++mi)
            af[mi] = *(const v8bf*)(As + (wr * 64 + mi * 16 + lrow) * BK + lq * 8);
#pragma unroll
        for (int nj = 0; nj < 4; ++nj)
            bfr[nj] = *(const v8bf*)(Bs + (wc * 64 + nj * 16 + lrow) * BK + lq * 8);
#pragma unroll
        for (int mi = 0; mi < 4; ++mi)
#pragma unroll
            for (int nj = 0; nj < 4; ++nj)
                acc[mi][nj] = __builtin_amdgcn_mfma_f32_16x16x32_bf16(
                    af[mi], bfr[nj], acc[mi][nj], 0, 0, 0);
    }

    const float sw = wscale[0];   // pre-clipped mean|w|
#pragma unroll
    for (int mi = 0; mi < 4; ++mi) {
#pragma unroll
        for (int r = 0; r < 4; ++r) {
            const int row = m0 + wr * 64 + mi * 16 + lq * 4 + r;
            const float rs = sw * rowscale[row];
#pragma unroll
            for (int nj = 0; nj < 4; ++nj) {
                const int col = n0 + wc * 64 + nj * 16 + lrow;
                float v = acc[mi][nj][r] * rs;
                if (EPI == 0) {
                    ((float*)Cv)[(size_t)row * N + col] = v;
                } else if (EPI == 1) {
                    v = fmaxf(v, 0.f); v = v * v;
                    ((half_t*)Cv)[(size_t)row * N + col] = (half_t)v;
                } else {
                    v = fmaxf(v, 0.f); v = v * v;
                    ((float*)Cv)[(size_t)row * N + col] = v;
                }
            }
        }
    }
}

extern "C" void kernel_launch(void* const* d_in, const int* in_sizes, int n_in,
                              void* d_out, int out_size, void* d_ws, size_t ws_size,
                              hipStream_t stream) {
    const float* x   = (const float*)d_in[0];   // [T, H] fp32
    const float* wup = (const float*)d_in[1];   // [I, H] fp32
    const float* wdn = (const float*)d_in[2];   // [H, I] fp32

    const int H = 2048;
    const int T = in_sizes[0] / H;              // 16384
    const int I = in_sizes[1] / H;              // 4096
    const long nw = (long)in_sizes[1];          // 8388608
    const float winv = 1.0f / (float)nw;

    char* p = (char*)d_ws;
    float* scales  = (float*)p;                 // 2 floats (pre-clipped s_up, s_dn)
    float* part_up = (float*)(p + 256);         // 256 floats
    float* part_dn = (float*)(p + 1280);        // 256 floats
    float* a_scale = (float*)(p + 2304);        // T
    float* h_scale = a_scale + T;               // T
    float* h_recip = h_scale + T;               // T
    size_t off = 2304 + (size_t)12 * T;
    off = (off + 255) & ~(size_t)255;
    u16* xq  = (u16*)(p + off); off += (size_t)T * H * 2;
    u16* wqu = (u16*)(p + off); off += (size_t)I * H * 2;
    u16* wqd = (u16*)(p + off); off += (size_t)H * I * 2;
    void* h  = (void*)(p + off);
    const bool h32 = (ws_size == 0) || (off + (size_t)T * I * 4 <= ws_size);

    // deterministic mean|w|: per-block partials, then fixed-order combine
    abssum_partial<<<256, 256, 0, stream>>>(wup, nw, part_up);
    abssum_partial<<<256, 256, 0, stream>>>(wdn, nw, part_dn);
    abssum_final<<<1, 128, 0, stream>>>(part_up, part_dn, scales, winv);

    int wblocks = (int)(nw / 2048);
    wquant_kernel<<<wblocks, 256, 0, stream>>>(wup, wqu, scales + 0);
    wquant_kernel<<<wblocks, 256, 0, stream>>>(wdn, wqd, scales + 1);

    aquant_kernel<<<T, 256, 0, stream>>>(x, xq, a_scale);

    if (h32) {
        gemm_bt<0, 2><<<dim3(I / BN, T / BM), 256, 0, stream>>>(
            xq, wqu, h, a_scale, nullptr, scales + 0, T, I, H);
        hamax_kernel<float, 2><<<T, 256, 0, stream>>>((const float*)h, h_scale, h_recip);
        gemm_bt<1, 0><<<dim3(H / BN, T / BM), 256, 0, stream>>>(
            h, wqd, d_out, h_scale, h_recip, scales + 1, T, H, I);
    } else {
        gemm_bt<0, 1><<<dim3(I / BN, T / BM), 256, 0, stream>>>(
            xq, wqu, h, a_scale, nullptr, scales + 0, T, I, H);
        hamax_kernel<half_t, 2><<<T, 256, 0, stream>>>((const half_t*)h, h_scale, h_recip);
        gemm_bt<2, 0><<<dim3(H / BN, T / BM), 256, 0, stream>>>(
            h, wqd, d_out, h_scale, h_recip, scales + 1, T, H, I);
    }
}